// Round 9
// baseline (596.105 us; speedup 1.0000x reference)
//
#include <hip/hip_runtime.h>
#include <hip/hip_bf16.h>

#define DIM 768
#define HEADS 8
#define HD 96
#define HIDDEN 1500
#define HPAD 1536            // HIDDEN padded to multiple of 128 (N) / 64 (K)
#define NB 8
#define NSEQ 1024
#define NTOK (NB * NSEQ)     // 8192
#define LNEPS 1e-5f
// quirk: scores / (hd^-0.5) == scores * sqrt(96)
#define ATTN_SCALE 9.797958971132712f

typedef __attribute__((ext_vector_type(4))) float f32x4;
typedef __attribute__((ext_vector_type(8))) __bf16 bf16x8;
typedef __attribute__((ext_vector_type(4))) __bf16 bf16x4;

// address-space pointer types for global_load_lds
typedef __attribute__((address_space(1))) const unsigned int GU32;
typedef __attribute__((address_space(3))) unsigned int LU32;

__device__ __forceinline__ void gload16(const void* g, void* l) {
    __builtin_amdgcn_global_load_lds((GU32*)g, (LU32*)l, 16, 0, 0);
}

// Dual-dtype load: flag-selected bf16 or fp32 interpretation of the same buffer.
__device__ __forceinline__ float ldsel(const void* p, size_t i, bool bf) {
    return bf ? __bfloat162float(((const __hip_bfloat16*)p)[i])
              : ((const float*)p)[i];
}

__device__ __forceinline__ float gelu_exact(float x) {
    return 0.5f * x * (1.0f + erff(x * 0.7071067811865476f));
}

// ---------------------------------------------------------------------------
// dtype detector: ln_g == ones. fp32 ones -> word 0x3F800000; bf16 pair -> 0x3F803F80.
// ---------------------------------------------------------------------------
__global__ void detect_kernel(const unsigned int* __restrict__ g, int* __restrict__ flag) {
    *flag = (g[0] == 0x3F800000u) ? 0 : 1;   // 1 => buffers are bf16
}

// ---------------------------------------------------------------------------
// LayerNorm: one block per row of 768. INDUAL: x is dual-dtype; else fp32.
// Output: split bf16 hi/lo planes (feeds MFMA GEMM A-operand).
// ---------------------------------------------------------------------------
template <int INDUAL>
__global__ __launch_bounds__(256) void ln_kernel(const void* __restrict__ x,
                                                 const void* __restrict__ gam,
                                                 const void* __restrict__ bet,
                                                 __bf16* __restrict__ outH,
                                                 __bf16* __restrict__ outL,
                                                 const int* __restrict__ flagp) {
    bool bf = (*flagp != 0);
    int row = blockIdx.x;
    int t = threadIdx.x;
    size_t base = (size_t)row * DIM;
    float v0, v1, v2;
    if (INDUAL) {
        v0 = ldsel(x, base + t, bf);
        v1 = ldsel(x, base + t + 256, bf);
        v2 = ldsel(x, base + t + 512, bf);
    } else {
        const float* xr = (const float*)x + base;
        v0 = xr[t]; v1 = xr[t + 256]; v2 = xr[t + 512];
    }
    float s = v0 + v1 + v2;
    float s2 = v0 * v0 + v1 * v1 + v2 * v2;
    __shared__ float r1[256];
    __shared__ float r2[256];
    r1[t] = s; r2[t] = s2;
    __syncthreads();
    for (int o = 128; o > 0; o >>= 1) {
        if (t < o) { r1[t] += r1[t + o]; r2[t] += r2[t + o]; }
        __syncthreads();
    }
    float mean = r1[0] * (1.0f / DIM);
    float var = r2[0] * (1.0f / DIM) - mean * mean;
    float inv = rsqrtf(var + LNEPS);
    float o0 = (v0 - mean) * inv * ldsel(gam, t, bf)       + ldsel(bet, t, bf);
    float o1 = (v1 - mean) * inv * ldsel(gam, t + 256, bf) + ldsel(bet, t + 256, bf);
    float o2 = (v2 - mean) * inv * ldsel(gam, t + 512, bf) + ldsel(bet, t + 512, bf);
    __bf16 h0 = (__bf16)o0; outH[base + t]       = h0; outL[base + t]       = (__bf16)(o0 - (float)h0);
    __bf16 h1 = (__bf16)o1; outH[base + t + 256] = h1; outL[base + t + 256] = (__bf16)(o1 - (float)h1);
    __bf16 h2 = (__bf16)o2; outH[base + t + 512] = h2; outL[base + t + 512] = (__bf16)(o2 - (float)h2);
}

// ---------------------------------------------------------------------------
// Weight transpose + bf16 hi/lo split.  W: [K][N] dual-dtype (row-major).
// Out: WT hi/lo [Ngrid][Kpad] bf16, zero-padded.
// ---------------------------------------------------------------------------
__global__ __launch_bounds__(256) void wsplit_kernel(const void* __restrict__ W,
                                                     __bf16* __restrict__ WTh,
                                                     __bf16* __restrict__ WTl,
                                                     int K, int N, int Kpad, int Ngrid,
                                                     const int* __restrict__ flagp) {
    bool bf = (*flagp != 0);
    __shared__ float T[32][33];
    int tx = threadIdx.x & 31, ty = threadIdx.x >> 5;
    int k0 = blockIdx.x * 32, n0 = blockIdx.y * 32;
#pragma unroll
    for (int i = 0; i < 4; ++i) {
        int k = k0 + ty + i * 8, n = n0 + tx;
        T[ty + i * 8][tx] = (k < K && n < N) ? ldsel(W, (size_t)k * N + n, bf) : 0.0f;
    }
    __syncthreads();
#pragma unroll
    for (int i = 0; i < 4; ++i) {
        int n = n0 + ty + i * 8, k = k0 + tx;
        if (n < Ngrid && k < Kpad) {
            float v = T[tx][ty + i * 8];
            __bf16 h = (__bf16)v;
            WTh[(size_t)n * Kpad + k] = h;
            WTl[(size_t)n * Kpad + k] = (__bf16)(v - (float)h);
        }
    }
}

// ---------------------------------------------------------------------------
// K-plane conversion pre-pass: qkv fp32 -> Kh/Kl bf16 planes [bh][key][96].
// ---------------------------------------------------------------------------
__global__ __launch_bounds__(256) void kconv_kernel(const float* __restrict__ qkv,
                                                    __bf16* __restrict__ Khg,
                                                    __bf16* __restrict__ Klg) {
    int bh = blockIdx.x;              // 0..63
    int kb = blockIdx.y;              // 0..7
    int b = bh >> 3, h = bh & 7;
    int t = threadIdx.x;
    const size_t rs = 3 * DIM;
    const float* kg = qkv + ((size_t)b * NSEQ + kb * 128) * rs + DIM + h * HD;
    __bf16* oh = Khg + ((size_t)bh * NSEQ + kb * 128) * HD;
    __bf16* ol = Klg + ((size_t)bh * NSEQ + kb * 128) * HD;
#pragma unroll
    for (int i = 0; i < 12; ++i) {    // 128 keys x 24 f32x4-units = 3072
        int u = t + i * 256;
        int key = u / 24, dp = u % 24;
        f32x4 v = *(const f32x4*)(kg + (size_t)key * rs + dp * 4);
        bf16x4 h4, l4;
#pragma unroll
        for (int j = 0; j < 4; ++j) {
            __bf16 hi = (__bf16)v[j];
            h4[j] = hi;
            l4[j] = (__bf16)(v[j] - (float)hi);
        }
        *(bf16x4*)(oh + (size_t)key * HD + dp * 4) = h4;
        *(bf16x4*)(ol + (size_t)key * HD + dp * 4) = l4;
    }
}

// ---------------------------------------------------------------------------
// MFMA GEMM, error-compensated split-bf16 (round-6/8 proven version).
//   D = Ah*Bh + Al*Bh + (Ah*Bl if weights fp32)  -> ~2^-16 rel error.
// 128x128 tile, BK=64, 256 thr = 4 waves, 16x16x32 bf16 MFMA.
// global_load_lds width=16 staging; source-side swizzle (rule 21).
// BL staged only when weights fp32. XCD-aware bijective block swizzle.
// Pinned lessons: launch_bounds (256,2) [r5]; BK=64 [r7].
// ---------------------------------------------------------------------------
template <int ACT, int RES, int OUTMODE>
__global__ __launch_bounds__(256, 2) void gemm_kernel(
    const __bf16* __restrict__ AH, const __bf16* __restrict__ AL,
    const __bf16* __restrict__ BH, const __bf16* __restrict__ BL,
    const void* __restrict__ bias,
    const void* __restrict__ resv, int rstride,
    void* __restrict__ outv, int ostride,
    int K, int Nvalid,
    const int* __restrict__ flagp) {
    bool bf = (*flagp != 0);
    __shared__ __align__(16) __bf16 lds[4 * 8192];   // AH | AL | BH | BL planes, 16KB each
    __bf16* sAH = lds;
    __bf16* sAL = lds + 8192;
    __bf16* sBH = lds + 16384;
    __bf16* sBL = lds + 24576;

    int t = threadIdx.x;
    int lane = t & 63, w = t >> 6;
    int wr = w >> 1, wc = w & 1;            // wave grid 2x2, 64x64 each
    int lr = lane & 15, kq = lane >> 4;

    // XCD-aware bijective block swizzle.
    int gx = gridDim.x;
    int nwg = gx * gridDim.y;
    int orig = blockIdx.y * gx + blockIdx.x;
    int qq = nwg >> 3, rm = nwg & 7;
    int xcd = orig & 7, loc = orig >> 3;
    int wgid = (xcd < rm ? xcd * (qq + 1) : rm * (qq + 1) + (xcd - rm) * qq) + loc;
    int row0 = (wgid / gx) * 128, col0 = (wgid % gx) * 128;

    size_t asrc[4], bsrc[4];
    int ldst[4];
#pragma unroll
    for (int j = 0; j < 4; ++j) {
        int c = j * 256 + t;
        int rr = c >> 3;
        int kbs = (c & 7) ^ (rr & 7);
        asrc[j] = (size_t)(row0 + rr) * K + kbs * 8;
        bsrc[j] = (size_t)(col0 + rr) * K + kbs * 8;
        ldst[j] = c * 8;                    // linear LDS element offset
    }

    f32x4 acc[4][4];
#pragma unroll
    for (int mi = 0; mi < 4; ++mi)
#pragma unroll
        for (int ni = 0; ni < 4; ++ni)
            acc[mi][ni] = (f32x4){0.f, 0.f, 0.f, 0.f};

    for (int k0 = 0; k0 < K; k0 += 64) {
        __syncthreads();                     // readers of previous tile done
#pragma unroll
        for (int j = 0; j < 4; ++j) {
            gload16(AH + asrc[j] + k0, sAH + ldst[j]);
            gload16(AL + asrc[j] + k0, sAL + ldst[j]);
            gload16(BH + bsrc[j] + k0, sBH + ldst[j]);
            if (!bf) gload16(BL + bsrc[j] + k0, sBL + ldst[j]);
        }
        __syncthreads();                     // compiler drains vmcnt before barrier
#pragma unroll
        for (int s = 0; s < 2; ++s) {
            bf16x8 af_h[4], af_l[4], bt_h[4], bt_l[4];
            int kb = s * 4 + kq;
#pragma unroll
            for (int mi = 0; mi < 4; ++mi) {
                int rowm = wr * 64 + mi * 16 + lr;
                int off = (rowm * 8 + (kb ^ (rowm & 7))) * 8;
                af_h[mi] = *(const bf16x8*)(sAH + off);
                af_l[mi] = *(const bf16x8*)(sAL + off);
            }
#pragma unroll
            for (int ni = 0; ni < 4; ++ni) {
                int rown = wc * 64 + ni * 16 + lr;
                int off = (rown * 8 + (kb ^ (rown & 7))) * 8;
                bt_h[ni] = *(const bf16x8*)(sBH + off);
                bt_l[ni] = *(const bf16x8*)(sBL + off);
            }
            if (!bf) {
#pragma unroll
                for (int mi = 0; mi < 4; ++mi)
#pragma unroll
                    for (int ni = 0; ni < 4; ++ni) {
                        acc[mi][ni] = __builtin_amdgcn_mfma_f32_16x16x32_bf16(af_h[mi], bt_h[ni], acc[mi][ni], 0, 0, 0);
                        acc[mi][ni] = __builtin_amdgcn_mfma_f32_16x16x32_bf16(af_l[mi], bt_h[ni], acc[mi][ni], 0, 0, 0);
                        acc[mi][ni] = __builtin_amdgcn_mfma_f32_16x16x32_bf16(af_h[mi], bt_l[ni], acc[mi][ni], 0, 0, 0);
                    }
            } else {
#pragma unroll
                for (int mi = 0; mi < 4; ++mi)
#pragma unroll
                    for (int ni = 0; ni < 4; ++ni) {
                        acc[mi][ni] = __builtin_amdgcn_mfma_f32_16x16x32_bf16(af_h[mi], bt_h[ni], acc[mi][ni], 0, 0, 0);
                        acc[mi][ni] = __builtin_amdgcn_mfma_f32_16x16x32_bf16(af_l[mi], bt_h[ni], acc[mi][ni], 0, 0, 0);
                    }
            }
        }
    }

    // Epilogue. C/D layout: lane reg j -> row fq*4+j, col fr.
    int fr = lane & 15, fq = lane >> 4;
#pragma unroll
    for (int mi = 0; mi < 4; ++mi) {
#pragma unroll
        for (int ni = 0; ni < 4; ++ni) {
            int cc = col0 + wc * 64 + ni * 16 + fr;
#pragma unroll
            for (int j = 0; j < 4; ++j) {
                int rr = row0 + wr * 64 + mi * 16 + fq * 4 + j;
                if (cc < Nvalid) {
                    float cval = acc[mi][ni][j] + ldsel(bias, cc, bf);
                    if (ACT == 1) cval = gelu_exact(cval);
                    if (RES == 1) cval += ldsel(resv, (size_t)rr * rstride + cc, bf);
                    if (RES == 2) cval += ((const float*)resv)[(size_t)rr * rstride + cc];
                    if (OUTMODE == 0) {
                        ((float*)outv)[(size_t)rr * ostride + cc] = cval;
                    } else if (OUTMODE == 1) {
                        if (bf)
                            ((__hip_bfloat16*)outv)[(size_t)rr * ostride + cc] = __float2bfloat16(cval);
                        else
                            ((float*)outv)[(size_t)rr * ostride + cc] = cval;
                    } else {
                        __bf16 hv = (__bf16)cval;
                        ((__bf16*)outv)[(size_t)rr * ostride + cc] = hv;
                        ((__bf16*)outv)[(size_t)NTOK * HPAD + (size_t)rr * ostride + cc] =
                            (__bf16)(cval - (float)hv);
                    }
                } else if (OUTMODE == 2) {
                    ((__bf16*)outv)[(size_t)rr * ostride + cc] = (__bf16)0.0f;
                    ((__bf16*)outv)[(size_t)NTOK * HPAD + (size_t)rr * ostride + cc] = (__bf16)0.0f;
                }
            }
        }
    }
}

// ---------------------------------------------------------------------------
// MFMA flash attention, QBLK=128: 512 thr = 8 waves, each wave owns 16 q-rows
// (per-wave code identical to the proven 4-wave version). K/V staged ONCE per
// 128 q-rows (was 64) -> chip-total staging & K/V fetch halve; grid 512 = 2/CU.
// Staging partition: t<192 (waves 0-2) V as before; 192<=t<448 (waves 3-6) K;
// wave 7 idle in staging. QK^T 3-term hi/lo; PV single-bf16 P,V.
// Vt rows 160 B (empirically best, r6/r7 -- do not re-derive).
// LDS: K 2x13312 + Vt 15360 + P 128x144 = 60416 B -> 2 blocks/CU, 16 waves/CU.
// __launch_bounds__(512,4): VGPR cap 128, natural use ~90 (safe margin, r5).
// ---------------------------------------------------------------------------
__global__ __launch_bounds__(512, 4) void attn_kernel(const float* __restrict__ qkv,
                                                      const __bf16* __restrict__ Khg,
                                                      const __bf16* __restrict__ Klg,
                                                      __bf16* __restrict__ oH,
                                                      __bf16* __restrict__ oL) {
    __shared__ __align__(16) char smem[60416];
    char* Kh_s = smem;                // 64*208 = 13312
    char* Kl_s = smem + 13312;        // 13312
    char* Vt_s = smem + 26624;        // 96*160 = 15360
    char* P_s  = smem + 41984;        // 128*144 = 18432  -> total 60416

    // XCD swizzle (nwg = 512, divisible by 8)
    int nwg = gridDim.x * gridDim.y;
    int orig = blockIdx.y * gridDim.x + blockIdx.x;
    int qq = nwg >> 3;
    int wgid = (orig & 7) * qq + (orig >> 3);
    int qt = wgid & 7;                // 0..7 (128-row q tile)
    int bh = wgid >> 3;               // 0..63
    int b = bh >> 3, h = bh & 7;
    int t = threadIdx.x;
    int lane = t & 63, w = t >> 6;    // wave id 0..7
    int r = lane & 15, g = lane >> 4; // fragment row / k-group

    const size_t rs = 3 * DIM;        // 2304

    // ---- Q into registers (hi/lo), rows qt*128 + w*16 + r, 3 k-chunks of 32 ----
    bf16x8 qh[3], ql[3];
    {
        const float* qp = qkv + ((size_t)b * NSEQ + qt * 128 + w * 16 + r) * rs + h * HD;
#pragma unroll
        for (int kc = 0; kc < 3; ++kc) {
            f32x4 f0 = *(const f32x4*)(qp + kc * 32 + g * 8);
            f32x4 f1 = *(const f32x4*)(qp + kc * 32 + g * 8 + 4);
#pragma unroll
            for (int j = 0; j < 8; ++j) {
                float f = (j < 4) ? f0[j] : f1[j - 4];
                __bf16 hi = (__bf16)f;
                qh[kc][j] = hi;
                ql[kc][j] = (__bf16)(f - (float)hi);
            }
        }
    }

    // staging registers: V for t<192 (8 f32x4); K planes for 192<=t<448 (3+3 bf16x8)
    bf16x8 khreg[3], klreg[3];
    f32x4 vreg[8];
    const __bf16* khg0 = Khg + (size_t)bh * NSEQ * HD;
    const __bf16* klg0 = Klg + (size_t)bh * NSEQ * HD;
    const float* vg0 = qkv + (size_t)b * NSEQ * rs + 2 * DIM + h * HD;
    int vdq = t >> 3, voct = t & 7;   // valid when t < 192
    int tk = t - 192;                 // valid when 192 <= t < 448

    auto load_kv = [&](int jt) {
        if (t < 192) {
            const float* vg = vg0 + (size_t)(jt * 64) * rs;
#pragma unroll
            for (int koff = 0; koff < 8; ++koff)
                vreg[koff] = *(const f32x4*)(vg + (size_t)(voct * 8 + koff) * rs + vdq * 4);
        } else if (t < 448) {
#pragma unroll
            for (int i = 0; i < 3; ++i) {
                int u = tk + i * 256;          // 64 keys x 12 16B-units = 768
                int key = u / 12, un = u % 12;
                khreg[i] = *(const bf16x8*)(khg0 + (size_t)(jt * 64 + key) * HD + un * 8);
                klreg[i] = *(const bf16x8*)(klg0 + (size_t)(jt * 64 + key) * HD + un * 8);
            }
        }
    };

    auto store_kv = [&]() {
        if (t < 192) {
#pragma unroll
            for (int j = 0; j < 4; ++j) {
                bf16x8 vrow;
#pragma unroll
                for (int koff = 0; koff < 8; ++koff)
                    vrow[koff] = (__bf16)vreg[koff][j];
                *(bf16x8*)(Vt_s + (vdq * 4 + j) * 160 + voct * 16) = vrow;
            }
        } else if (t < 448) {
#pragma unroll
            for (int i = 0; i < 3; ++i) {
                int u = tk + i * 256;
                int key = u / 12, un = u % 12;
                *(bf16x8*)(Kh_s + key * 208 + un * 16) = khreg[i];
                *(bf16x8*)(Kl_s + key * 208 + un * 16) = klreg[i];
            }
        }
    };

    f32x4 o[6];
#pragma unroll
    for (int di = 0; di < 6; ++di) o[di] = (f32x4){0.f, 0.f, 0.f, 0.f};
    float m_i[4], l_i[4];
#pragma unroll
    for (int jj = 0; jj < 4; ++jj) { m_i[jj] = -1e30f; l_i[jj] = 0.0f; }

    load_kv(0);
    for (int jt = 0; jt < NSEQ / 64; ++jt) {
        __syncthreads();   // prev tile's K/Vt reads complete before overwrite
        store_kv();        // (compiler inserts vmcnt wait on staging regs here)
        __syncthreads();
        if (jt + 1 < NSEQ / 64) load_kv(jt + 1);   // prefetch under compute

        // ---- S = Q K^T (3-term), 16x64 per wave ----
        f32x4 sacc[4];
#pragma unroll
        for (int ci = 0; ci < 4; ++ci) sacc[ci] = (f32x4){0.f, 0.f, 0.f, 0.f};
#pragma unroll
        for (int ci = 0; ci < 4; ++ci) {
#pragma unroll
            for (int kc = 0; kc < 3; ++kc) {
                bf16x8 kh = *(const bf16x8*)(Kh_s + (ci * 16 + r) * 208 + kc * 64 + g * 16);
                bf16x8 kl = *(const bf16x8*)(Kl_s + (ci * 16 + r) * 208 + kc * 64 + g * 16);
                sacc[ci] = __builtin_amdgcn_mfma_f32_16x16x32_bf16(qh[kc], kh, sacc[ci], 0, 0, 0);
                sacc[ci] = __builtin_amdgcn_mfma_f32_16x16x32_bf16(ql[kc], kh, sacc[ci], 0, 0, 0);
                sacc[ci] = __builtin_amdgcn_mfma_f32_16x16x32_bf16(qh[kc], kl, sacc[ci], 0, 0, 0);
            }
        }

        // ---- online softmax. lane holds rows q = w*16 + g*4 + jj, col ci*16+r ----
        float p[4][4];
        float al[4];
#pragma unroll
        for (int jj = 0; jj < 4; ++jj) {
            float s0 = sacc[0][jj] * ATTN_SCALE;
            float s1 = sacc[1][jj] * ATTN_SCALE;
            float s2 = sacc[2][jj] * ATTN_SCALE;
            float s3 = sacc[3][jj] * ATTN_SCALE;
            float mx = fmaxf(fmaxf(s0, s1), fmaxf(s2, s3));
            mx = fmaxf(mx, __shfl_xor(mx, 1));
            mx = fmaxf(mx, __shfl_xor(mx, 2));
            mx = fmaxf(mx, __shfl_xor(mx, 4));
            mx = fmaxf(mx, __shfl_xor(mx, 8));
            float mn = fmaxf(m_i[jj], mx);
            al[jj] = __expf(m_i[jj] - mn);
            p[0][jj] = __expf(s0 - mn);
            p[1][jj] = __expf(s1 - mn);
            p[2][jj] = __expf(s2 - mn);
            p[3][jj] = __expf(s3 - mn);
            float rsm = p[0][jj] + p[1][jj] + p[2][jj] + p[3][jj];
            rsm += __shfl_xor(rsm, 1);
            rsm += __shfl_xor(rsm, 2);
            rsm += __shfl_xor(rsm, 4);
            rsm += __shfl_xor(rsm, 8);
            l_i[jj] = l_i[jj] * al[jj] + rsm;
            m_i[jj] = mn;
        }
        // O rescale
#pragma unroll
        for (int di = 0; di < 6; ++di)
#pragma unroll
            for (int jj = 0; jj < 4; ++jj) o[di][jj] *= al[jj];
        // write P (bf16), rows w*16+g*4+jj, cols ci*16+r (row stride 144 B)
#pragma unroll
        for (int jj = 0; jj < 4; ++jj)
#pragma unroll
            for (int ci = 0; ci < 4; ++ci)
                ((__bf16*)(P_s + (w * 16 + g * 4 + jj) * 144))[ci * 16 + r] = (__bf16)p[ci][jj];
        // same-wave LDS FIFO ordering; keep compiler from reordering
        asm volatile("" ::: "memory");

        // ---- O += P V ----
        bf16x8 pa[2];
#pragma unroll
        for (int kc2 = 0; kc2 < 2; ++kc2)
            pa[kc2] = *(const bf16x8*)(P_s + (w * 16 + r) * 144 + kc2 * 64 + g * 16);
#pragma unroll
        for (int di = 0; di < 6; ++di) {
#pragma unroll
            for (int kc2 = 0; kc2 < 2; ++kc2) {
                bf16x8 vb = *(const bf16x8*)(Vt_s + (di * 16 + r) * 160 + kc2 * 64 + g * 16);
                o[di] = __builtin_amdgcn_mfma_f32_16x16x32_bf16(pa[kc2], vb, o[di], 0, 0, 0);
            }
        }
    }

    // ---- epilogue: out[tok][h*96+d] hi/lo planes ----
    float invl[4];
#pragma unroll
    for (int jj = 0; jj < 4; ++jj) invl[jj] = 1.0f / l_i[jj];
#pragma unroll
    for (int jj = 0; jj < 4; ++jj) {
        size_t tok = (size_t)b * NSEQ + (size_t)qt * 128 + w * 16 + g * 4 + jj;
        size_t base = tok * DIM + h * HD + r;
#pragma unroll
        for (int di = 0; di < 6; ++di) {
            float v = o[di][jj] * invl[jj];
            __bf16 hv = (__bf16)v;
            oH[base + di * 16] = hv;
            oL[base + di * 16] = (__bf16)(v - (float)hv);
        }
    }
}

// ---------------------------------------------------------------------------
// Workspace (fp32 units; total NTOK*3840 floats + flag):
//  R0 [0, NTOK*768)            : ylnH|ylnL -> attnH|attnL -> klnH|klnL (bf16 planes)
//  R1 [NTOK*768, NTOK*3072)    : qkv fp32 [NTOK][2304] -> W0T|W1T|W2T + h planes
//  R2 [NTOK*3072, NTOK*3840)   : WqkvT split -> Khg|Klg bf16 planes -> z fp32
// ---------------------------------------------------------------------------
extern "C" void kernel_launch(void* const* d_in, const int* in_sizes, int n_in,
                              void* d_out, int out_size, void* d_ws, size_t ws_size,
                              hipStream_t stream) {
    const void* x    = d_in[0];
    const void* ln_g = d_in[1];
    const void* ln_b = d_in[2];
    const void* Wqkv = d_in[3];
    const void* bqkv = d_in[4];
    const void* W0   = d_in[5];
    const void* b0   = d_in[6];
    const void* W1   = d_in[7];
    const void* b1   = d_in[8];
    const void* W2   = d_in[9];
    const void* b2   = d_in[10];

    float* ws = (float*)d_ws;
    // R0
    __bf16* ylnH = (__bf16*)ws;
    __bf16* ylnL = ylnH + (size_t)NTOK * DIM;
    __bf16* atnH = ylnH;
    __bf16* atnL = ylnL;
    __bf16* klnH = ylnH;
    __bf16* klnL = ylnL;
    // R1: qkv fp32, then post-attention overlay
    float* qkv = ws + (size_t)NTOK * DIM;      // [NTOK][2304] fp32
    __bf16* r1 = (__bf16*)qkv;                 // qkv dead after attention
    __bf16* W0Th = r1;
    __bf16* W0Tl = W0Th + (size_t)768 * 768;
    __bf16* W1Th = W0Tl + (size_t)768 * 768;   // [HPAD][768]
    __bf16* W1Tl = W1Th + (size_t)HPAD * 768;
    __bf16* W2Th = W1Tl + (size_t)HPAD * 768;  // [768][HPAD]
    __bf16* W2Tl = W2Th + (size_t)768 * HPAD;
    __bf16* hH   = W2Tl + (size_t)768 * HPAD;  // [NTOK][HPAD] + lo plane
    __bf16* hL   = hH + (size_t)NTOK * HPAD;   // total 31.06M bf16 <= 37.75M avail
    // R2
    float* zbuf = ws + (size_t)NTOK * (DIM + 3 * DIM);
    __bf16* WqkvTh = (__bf16*)zbuf;            // dead after step 2
    __bf16* WqkvTl = WqkvTh + (size_t)(3 * DIM) * DIM;
    __bf16* Khg = (__bf16*)zbuf;               // overlays WqkvT after step 2
    __bf16* Klg = Khg + (size_t)64 * NSEQ * HD;  // ends exactly at R2 end

    int* flag = (int*)(ws + (size_t)NTOK * 3840);

    // 0. detect dtype
    detect_kernel<<<1, 1, 0, stream>>>((const unsigned int*)ln_g, flag);
    // 1. y_ln = LN(x)  (split bf16)
    ln_kernel<1><<<NTOK, 256, 0, stream>>>(x, ln_g, ln_b, ylnH, ylnL, flag);
    // 1b. split+transpose Wqkv into R2
    wsplit_kernel<<<dim3(DIM / 32, (3 * DIM) / 32), 256, 0, stream>>>(
        Wqkv, WqkvTh, WqkvTl, DIM, 3 * DIM, DIM, 3 * DIM, flag);
    // 2. qkv = y_ln @ Wqkv + bqkv  (plain coalesced fp32 out)
    gemm_kernel<0, 0, 0><<<dim3((3 * DIM) / 128, NTOK / 128), 256, 0, stream>>>(
        ylnH, ylnL, WqkvTh, WqkvTl, bqkv, nullptr, 0, qkv, 3 * DIM, DIM, 3 * DIM, flag);
    // 2b. K plane conversion pre-pass (WqkvT now dead; Khg/Klg overlay it)
    kconv_kernel<<<dim3(NB * HEADS, NSEQ / 128), 256, 0, stream>>>(qkv, Khg, Klg);
    // 3. MFMA flash attention, QBLK=128 (split bf16 out)
    attn_kernel<<<dim3(NSEQ / 128, NB * HEADS), 512, 0, stream>>>(
        qkv, Khg, Klg, atnH, atnL);
    // 3b. split+transpose W0/W1/W2 into R1 (qkv dead)
    wsplit_kernel<<<dim3(DIM / 32, DIM / 32), 256, 0, stream>>>(
        W0, W0Th, W0Tl, DIM, DIM, DIM, DIM, flag);
    wsplit_kernel<<<dim3(DIM / 32, HPAD / 32), 256, 0, stream>>>(
        W1, W1Th, W1Tl, DIM, HIDDEN, DIM, HPAD, flag);
    wsplit_kernel<<<dim3(HPAD / 32, DIM / 32), 256, 0, stream>>>(
        W2, W2Th, W2Tl, HIDDEN, DIM, HPAD, DIM, flag);
    // 4. z = attn @ W0 + b0 + x  (fp32 out; overwrites Khg/Klg, both dead)
    gemm_kernel<0, 1, 0><<<dim3(DIM / 128, NTOK / 128), 256, 0, stream>>>(
        atnH, atnL, W0Th, W0Tl, b0, x, DIM, zbuf, DIM, DIM, DIM, flag);
    // 5. k_ln = LN(z)  (split bf16)
    ln_kernel<0><<<NTOK, 256, 0, stream>>>(zbuf, ln_g, ln_b, klnH, klnL, flag);
    // 6. h = gelu(k_ln @ W1 + b1)  (split bf16, zero-padded to HPAD)
    gemm_kernel<1, 0, 2><<<dim3(HPAD / 128, NTOK / 128), 256, 0, stream>>>(
        klnH, klnL, W1Th, W1Tl, b1, nullptr, 0, hH, HPAD, DIM, HIDDEN, flag);
    // 7. out = h @ W2 + b2 + z  (flag dtype; K over HPAD, pads zero)
    gemm_kernel<0, 2, 1><<<dim3(DIM / 128, NTOK / 128), 256, 0, stream>>>(
        hH, hL, W2Th, W2Tl, b2, zbuf, DIM, d_out, DIM, HPAD, DIM, flag);
}

// Round 10
// 557.697 us; speedup vs baseline: 1.0689x; 1.0689x over previous
//
#include <hip/hip_runtime.h>
#include <hip/hip_bf16.h>

#define DIM 768
#define HEADS 8
#define HD 96
#define HIDDEN 1500
#define HPAD 1536            // HIDDEN padded to multiple of 128 (N) / 64 (K)
#define NB 8
#define NSEQ 1024
#define NTOK (NB * NSEQ)     // 8192
#define LNEPS 1e-5f
// quirk: scores / (hd^-0.5) == scores * sqrt(96)
#define ATTN_SCALE 9.797958971132712f

typedef __attribute__((ext_vector_type(4))) float f32x4;
typedef __attribute__((ext_vector_type(8))) __bf16 bf16x8;
typedef __attribute__((ext_vector_type(4))) __bf16 bf16x4;

// address-space pointer types for global_load_lds
typedef __attribute__((address_space(1))) const unsigned int GU32;
typedef __attribute__((address_space(3))) unsigned int LU32;

__device__ __forceinline__ void gload16(const void* g, void* l) {
    __builtin_amdgcn_global_load_lds((GU32*)g, (LU32*)l, 16, 0, 0);
}

// Dual-dtype load: flag-selected bf16 or fp32 interpretation of the same buffer.
__device__ __forceinline__ float ldsel(const void* p, size_t i, bool bf) {
    return bf ? __bfloat162float(((const __hip_bfloat16*)p)[i])
              : ((const float*)p)[i];
}

__device__ __forceinline__ float gelu_exact(float x) {
    return 0.5f * x * (1.0f + erff(x * 0.7071067811865476f));
}

// ---------------------------------------------------------------------------
// dtype detector: ln_g == ones. fp32 ones -> word 0x3F800000; bf16 pair -> 0x3F803F80.
// ---------------------------------------------------------------------------
__global__ void detect_kernel(const unsigned int* __restrict__ g, int* __restrict__ flag) {
    *flag = (g[0] == 0x3F800000u) ? 0 : 1;   // 1 => buffers are bf16
}

// ---------------------------------------------------------------------------
// LayerNorm: one block per row of 768. INDUAL: x is dual-dtype; else fp32.
// Output: split bf16 hi/lo planes (feeds MFMA GEMM A-operand).
// ---------------------------------------------------------------------------
template <int INDUAL>
__global__ __launch_bounds__(256) void ln_kernel(const void* __restrict__ x,
                                                 const void* __restrict__ gam,
                                                 const void* __restrict__ bet,
                                                 __bf16* __restrict__ outH,
                                                 __bf16* __restrict__ outL,
                                                 const int* __restrict__ flagp) {
    bool bf = (*flagp != 0);
    int row = blockIdx.x;
    int t = threadIdx.x;
    size_t base = (size_t)row * DIM;
    float v0, v1, v2;
    if (INDUAL) {
        v0 = ldsel(x, base + t, bf);
        v1 = ldsel(x, base + t + 256, bf);
        v2 = ldsel(x, base + t + 512, bf);
    } else {
        const float* xr = (const float*)x + base;
        v0 = xr[t]; v1 = xr[t + 256]; v2 = xr[t + 512];
    }
    float s = v0 + v1 + v2;
    float s2 = v0 * v0 + v1 * v1 + v2 * v2;
    __shared__ float r1[256];
    __shared__ float r2[256];
    r1[t] = s; r2[t] = s2;
    __syncthreads();
    for (int o = 128; o > 0; o >>= 1) {
        if (t < o) { r1[t] += r1[t + o]; r2[t] += r2[t + o]; }
        __syncthreads();
    }
    float mean = r1[0] * (1.0f / DIM);
    float var = r2[0] * (1.0f / DIM) - mean * mean;
    float inv = rsqrtf(var + LNEPS);
    float o0 = (v0 - mean) * inv * ldsel(gam, t, bf)       + ldsel(bet, t, bf);
    float o1 = (v1 - mean) * inv * ldsel(gam, t + 256, bf) + ldsel(bet, t + 256, bf);
    float o2 = (v2 - mean) * inv * ldsel(gam, t + 512, bf) + ldsel(bet, t + 512, bf);
    __bf16 h0 = (__bf16)o0; outH[base + t]       = h0; outL[base + t]       = (__bf16)(o0 - (float)h0);
    __bf16 h1 = (__bf16)o1; outH[base + t + 256] = h1; outL[base + t + 256] = (__bf16)(o1 - (float)h1);
    __bf16 h2 = (__bf16)o2; outH[base + t + 512] = h2; outL[base + t + 512] = (__bf16)(o2 - (float)h2);
}

// ---------------------------------------------------------------------------
// Weight transpose + bf16 hi/lo split.  W: [K][N] dual-dtype (row-major).
// Out: WT hi/lo [Ngrid][Kpad] bf16, zero-padded.
// ---------------------------------------------------------------------------
__global__ __launch_bounds__(256) void wsplit_kernel(const void* __restrict__ W,
                                                     __bf16* __restrict__ WTh,
                                                     __bf16* __restrict__ WTl,
                                                     int K, int N, int Kpad, int Ngrid,
                                                     const int* __restrict__ flagp) {
    bool bf = (*flagp != 0);
    __shared__ float T[32][33];
    int tx = threadIdx.x & 31, ty = threadIdx.x >> 5;
    int k0 = blockIdx.x * 32, n0 = blockIdx.y * 32;
#pragma unroll
    for (int i = 0; i < 4; ++i) {
        int k = k0 + ty + i * 8, n = n0 + tx;
        T[ty + i * 8][tx] = (k < K && n < N) ? ldsel(W, (size_t)k * N + n, bf) : 0.0f;
    }
    __syncthreads();
#pragma unroll
    for (int i = 0; i < 4; ++i) {
        int n = n0 + ty + i * 8, k = k0 + tx;
        if (n < Ngrid && k < Kpad) {
            float v = T[tx][ty + i * 8];
            __bf16 h = (__bf16)v;
            WTh[(size_t)n * Kpad + k] = h;
            WTl[(size_t)n * Kpad + k] = (__bf16)(v - (float)h);
        }
    }
}

// ---------------------------------------------------------------------------
// K-plane conversion pre-pass: qkv fp32 -> Kh/Kl bf16 planes [bh][key][96].
// ---------------------------------------------------------------------------
__global__ __launch_bounds__(256) void kconv_kernel(const float* __restrict__ qkv,
                                                    __bf16* __restrict__ Khg,
                                                    __bf16* __restrict__ Klg) {
    int bh = blockIdx.x;              // 0..63
    int kb = blockIdx.y;              // 0..7
    int b = bh >> 3, h = bh & 7;
    int t = threadIdx.x;
    const size_t rs = 3 * DIM;
    const float* kg = qkv + ((size_t)b * NSEQ + kb * 128) * rs + DIM + h * HD;
    __bf16* oh = Khg + ((size_t)bh * NSEQ + kb * 128) * HD;
    __bf16* ol = Klg + ((size_t)bh * NSEQ + kb * 128) * HD;
#pragma unroll
    for (int i = 0; i < 12; ++i) {    // 128 keys x 24 f32x4-units = 3072
        int u = t + i * 256;
        int key = u / 24, dp = u % 24;
        f32x4 v = *(const f32x4*)(kg + (size_t)key * rs + dp * 4);
        bf16x4 h4, l4;
#pragma unroll
        for (int j = 0; j < 4; ++j) {
            __bf16 hi = (__bf16)v[j];
            h4[j] = hi;
            l4[j] = (__bf16)(v[j] - (float)hi);
        }
        *(bf16x4*)(oh + (size_t)key * HD + dp * 4) = h4;
        *(bf16x4*)(ol + (size_t)key * HD + dp * 4) = l4;
    }
}

// ---------------------------------------------------------------------------
// MFMA GEMM, error-compensated split-bf16 (round-6/8 proven version).
//   D = Ah*Bh + Al*Bh + (Ah*Bl if weights fp32)  -> ~2^-16 rel error.
// 128x128 tile, BK=64, 256 thr = 4 waves, 16x16x32 bf16 MFMA.
// global_load_lds width=16 staging; source-side swizzle (rule 21).
// BL staged only when weights fp32. XCD-aware bijective block swizzle.
// Pinned lessons: launch_bounds (256,2) [r5]; BK=64 [r7].
// ---------------------------------------------------------------------------
template <int ACT, int RES, int OUTMODE>
__global__ __launch_bounds__(256, 2) void gemm_kernel(
    const __bf16* __restrict__ AH, const __bf16* __restrict__ AL,
    const __bf16* __restrict__ BH, const __bf16* __restrict__ BL,
    const void* __restrict__ bias,
    const void* __restrict__ resv, int rstride,
    void* __restrict__ outv, int ostride,
    int K, int Nvalid,
    const int* __restrict__ flagp) {
    bool bf = (*flagp != 0);
    __shared__ __align__(16) __bf16 lds[4 * 8192];   // AH | AL | BH | BL planes, 16KB each
    __bf16* sAH = lds;
    __bf16* sAL = lds + 8192;
    __bf16* sBH = lds + 16384;
    __bf16* sBL = lds + 24576;

    int t = threadIdx.x;
    int lane = t & 63, w = t >> 6;
    int wr = w >> 1, wc = w & 1;            // wave grid 2x2, 64x64 each
    int lr = lane & 15, kq = lane >> 4;

    // XCD-aware bijective block swizzle.
    int gx = gridDim.x;
    int nwg = gx * gridDim.y;
    int orig = blockIdx.y * gx + blockIdx.x;
    int qq = nwg >> 3, rm = nwg & 7;
    int xcd = orig & 7, loc = orig >> 3;
    int wgid = (xcd < rm ? xcd * (qq + 1) : rm * (qq + 1) + (xcd - rm) * qq) + loc;
    int row0 = (wgid / gx) * 128, col0 = (wgid % gx) * 128;

    size_t asrc[4], bsrc[4];
    int ldst[4];
#pragma unroll
    for (int j = 0; j < 4; ++j) {
        int c = j * 256 + t;
        int rr = c >> 3;
        int kbs = (c & 7) ^ (rr & 7);
        asrc[j] = (size_t)(row0 + rr) * K + kbs * 8;
        bsrc[j] = (size_t)(col0 + rr) * K + kbs * 8;
        ldst[j] = c * 8;                    // linear LDS element offset
    }

    f32x4 acc[4][4];
#pragma unroll
    for (int mi = 0; mi < 4; ++mi)
#pragma unroll
        for (int ni = 0; ni < 4; ++ni)
            acc[mi][ni] = (f32x4){0.f, 0.f, 0.f, 0.f};

    for (int k0 = 0; k0 < K; k0 += 64) {
        __syncthreads();                     // readers of previous tile done
#pragma unroll
        for (int j = 0; j < 4; ++j) {
            gload16(AH + asrc[j] + k0, sAH + ldst[j]);
            gload16(AL + asrc[j] + k0, sAL + ldst[j]);
            gload16(BH + bsrc[j] + k0, sBH + ldst[j]);
            if (!bf) gload16(BL + bsrc[j] + k0, sBL + ldst[j]);
        }
        __syncthreads();                     // compiler drains vmcnt before barrier
#pragma unroll
        for (int s = 0; s < 2; ++s) {
            bf16x8 af_h[4], af_l[4], bt_h[4], bt_l[4];
            int kb = s * 4 + kq;
#pragma unroll
            for (int mi = 0; mi < 4; ++mi) {
                int rowm = wr * 64 + mi * 16 + lr;
                int off = (rowm * 8 + (kb ^ (rowm & 7))) * 8;
                af_h[mi] = *(const bf16x8*)(sAH + off);
                af_l[mi] = *(const bf16x8*)(sAL + off);
            }
#pragma unroll
            for (int ni = 0; ni < 4; ++ni) {
                int rown = wc * 64 + ni * 16 + lr;
                int off = (rown * 8 + (kb ^ (rown & 7))) * 8;
                bt_h[ni] = *(const bf16x8*)(sBH + off);
                bt_l[ni] = *(const bf16x8*)(sBL + off);
            }
            if (!bf) {
#pragma unroll
                for (int mi = 0; mi < 4; ++mi)
#pragma unroll
                    for (int ni = 0; ni < 4; ++ni) {
                        acc[mi][ni] = __builtin_amdgcn_mfma_f32_16x16x32_bf16(af_h[mi], bt_h[ni], acc[mi][ni], 0, 0, 0);
                        acc[mi][ni] = __builtin_amdgcn_mfma_f32_16x16x32_bf16(af_l[mi], bt_h[ni], acc[mi][ni], 0, 0, 0);
                        acc[mi][ni] = __builtin_amdgcn_mfma_f32_16x16x32_bf16(af_h[mi], bt_l[ni], acc[mi][ni], 0, 0, 0);
                    }
            } else {
#pragma unroll
                for (int mi = 0; mi < 4; ++mi)
#pragma unroll
                    for (int ni = 0; ni < 4; ++ni) {
                        acc[mi][ni] = __builtin_amdgcn_mfma_f32_16x16x32_bf16(af_h[mi], bt_h[ni], acc[mi][ni], 0, 0, 0);
                        acc[mi][ni] = __builtin_amdgcn_mfma_f32_16x16x32_bf16(af_l[mi], bt_h[ni], acc[mi][ni], 0, 0, 0);
                    }
            }
        }
    }

    // Epilogue. C/D layout: lane reg j -> row fq*4+j, col fr.
    int fr = lane & 15, fq = lane >> 4;
#pragma unroll
    for (int mi = 0; mi < 4; ++mi) {
#pragma unroll
        for (int ni = 0; ni < 4; ++ni) {
            int cc = col0 + wc * 64 + ni * 16 + fr;
#pragma unroll
            for (int j = 0; j < 4; ++j) {
                int rr = row0 + wr * 64 + mi * 16 + fq * 4 + j;
                if (cc < Nvalid) {
                    float cval = acc[mi][ni][j] + ldsel(bias, cc, bf);
                    if (ACT == 1) cval = gelu_exact(cval);
                    if (RES == 1) cval += ldsel(resv, (size_t)rr * rstride + cc, bf);
                    if (RES == 2) cval += ((const float*)resv)[(size_t)rr * rstride + cc];
                    if (OUTMODE == 0) {
                        ((float*)outv)[(size_t)rr * ostride + cc] = cval;
                    } else if (OUTMODE == 1) {
                        if (bf)
                            ((__hip_bfloat16*)outv)[(size_t)rr * ostride + cc] = __float2bfloat16(cval);
                        else
                            ((float*)outv)[(size_t)rr * ostride + cc] = cval;
                    } else {
                        __bf16 hv = (__bf16)cval;
                        ((__bf16*)outv)[(size_t)rr * ostride + cc] = hv;
                        ((__bf16*)outv)[(size_t)NTOK * HPAD + (size_t)rr * ostride + cc] =
                            (__bf16)(cval - (float)hv);
                    }
                } else if (OUTMODE == 2) {
                    ((__bf16*)outv)[(size_t)rr * ostride + cc] = (__bf16)0.0f;
                    ((__bf16*)outv)[(size_t)NTOK * HPAD + (size_t)rr * ostride + cc] = (__bf16)0.0f;
                }
            }
        }
    }
}

// ---------------------------------------------------------------------------
// MFMA flash attention, QBLK=128: 512 thr = 8 waves, each wave owns 16 q-rows
// (per-wave code identical to the proven r8 4-wave version). K/V staged ONCE
// per 128 q-rows -> chip-total staging & K/V fetch halve; grid 512 = 2/CU.
// Staging partition: t<192 (waves 0-2) V; 192<=t<448 (waves 3-6) K; wave 7
// idle in staging. QK^T 3-term hi/lo; PV single-bf16 P,V.
// Vt rows 160 B (empirically best, r6/r7 -- do not re-derive).
// LDS: K 2x13312 + Vt 15360 + P 128x144 = 60416 B -> 2 blocks/CU, 16 waves/CU.
// PINNED LESSON (r5, r9): NO second __launch_bounds__ arg EVER on this
// toolchain -- it acts as a min-BLOCKS/CU cap (CUDA semantics) and forced a
// 64-VGPR allocation -> 230 MB of scratch spills (r9: VGPR_Count=64,
// WRITE_SIZE 26->256 MB). Natural allocation ~84-100 VGPR, LDS-limited 2/CU.
// ---------------------------------------------------------------------------
__global__ __launch_bounds__(512) void attn_kernel(const float* __restrict__ qkv,
                                                   const __bf16* __restrict__ Khg,
                                                   const __bf16* __restrict__ Klg,
                                                   __bf16* __restrict__ oH,
                                                   __bf16* __restrict__ oL) {
    __shared__ __align__(16) char smem[60416];
    char* Kh_s = smem;                // 64*208 = 13312
    char* Kl_s = smem + 13312;        // 13312
    char* Vt_s = smem + 26624;        // 96*160 = 15360
    char* P_s  = smem + 41984;        // 128*144 = 18432  -> total 60416

    // XCD swizzle (nwg = 512, divisible by 8)
    int nwg = gridDim.x * gridDim.y;
    int orig = blockIdx.y * gridDim.x + blockIdx.x;
    int qq = nwg >> 3;
    int wgid = (orig & 7) * qq + (orig >> 3);
    int qt = wgid & 7;                // 0..7 (128-row q tile)
    int bh = wgid >> 3;               // 0..63
    int b = bh >> 3, h = bh & 7;
    int t = threadIdx.x;
    int lane = t & 63, w = t >> 6;    // wave id 0..7
    int r = lane & 15, g = lane >> 4; // fragment row / k-group

    const size_t rs = 3 * DIM;        // 2304

    // ---- Q into registers (hi/lo), rows qt*128 + w*16 + r, 3 k-chunks of 32 ----
    bf16x8 qh[3], ql[3];
    {
        const float* qp = qkv + ((size_t)b * NSEQ + qt * 128 + w * 16 + r) * rs + h * HD;
#pragma unroll
        for (int kc = 0; kc < 3; ++kc) {
            f32x4 f0 = *(const f32x4*)(qp + kc * 32 + g * 8);
            f32x4 f1 = *(const f32x4*)(qp + kc * 32 + g * 8 + 4);
#pragma unroll
            for (int j = 0; j < 8; ++j) {
                float f = (j < 4) ? f0[j] : f1[j - 4];
                __bf16 hi = (__bf16)f;
                qh[kc][j] = hi;
                ql[kc][j] = (__bf16)(f - (float)hi);
            }
        }
    }

    // staging registers: V for t<192 (8 f32x4); K planes for 192<=t<448 (3+3 bf16x8)
    bf16x8 khreg[3], klreg[3];
    f32x4 vreg[8];
    const __bf16* khg0 = Khg + (size_t)bh * NSEQ * HD;
    const __bf16* klg0 = Klg + (size_t)bh * NSEQ * HD;
    const float* vg0 = qkv + (size_t)b * NSEQ * rs + 2 * DIM + h * HD;
    int vdq = t >> 3, voct = t & 7;   // valid when t < 192
    int tk = t - 192;                 // valid when 192 <= t < 448

    auto load_kv = [&](int jt) {
        if (t < 192) {
            const float* vg = vg0 + (size_t)(jt * 64) * rs;
#pragma unroll
            for (int koff = 0; koff < 8; ++koff)
                vreg[koff] = *(const f32x4*)(vg + (size_t)(voct * 8 + koff) * rs + vdq * 4);
        } else if (t < 448) {
#pragma unroll
            for (int i = 0; i < 3; ++i) {
                int u = tk + i * 256;          // 64 keys x 12 16B-units = 768
                int key = u / 12, un = u % 12;
                khreg[i] = *(const bf16x8*)(khg0 + (size_t)(jt * 64 + key) * HD + un * 8);
                klreg[i] = *(const bf16x8*)(klg0 + (size_t)(jt * 64 + key) * HD + un * 8);
            }
        }
    };

    auto store_kv = [&]() {
        if (t < 192) {
#pragma unroll
            for (int j = 0; j < 4; ++j) {
                bf16x8 vrow;
#pragma unroll
                for (int koff = 0; koff < 8; ++koff)
                    vrow[koff] = (__bf16)vreg[koff][j];
                *(bf16x8*)(Vt_s + (vdq * 4 + j) * 160 + voct * 16) = vrow;
            }
        } else if (t < 448) {
#pragma unroll
            for (int i = 0; i < 3; ++i) {
                int u = tk + i * 256;
                int key = u / 12, un = u % 12;
                *(bf16x8*)(Kh_s + key * 208 + un * 16) = khreg[i];
                *(bf16x8*)(Kl_s + key * 208 + un * 16) = klreg[i];
            }
        }
    };

    f32x4 o[6];
#pragma unroll
    for (int di = 0; di < 6; ++di) o[di] = (f32x4){0.f, 0.f, 0.f, 0.f};
    float m_i[4], l_i[4];
#pragma unroll
    for (int jj = 0; jj < 4; ++jj) { m_i[jj] = -1e30f; l_i[jj] = 0.0f; }

    load_kv(0);
    for (int jt = 0; jt < NSEQ / 64; ++jt) {
        __syncthreads();   // prev tile's K/Vt reads complete before overwrite
        store_kv();        // (compiler inserts vmcnt wait on staging regs here)
        __syncthreads();
        if (jt + 1 < NSEQ / 64) load_kv(jt + 1);   // prefetch under compute

        // ---- S = Q K^T (3-term), 16x64 per wave ----
        f32x4 sacc[4];
#pragma unroll
        for (int ci = 0; ci < 4; ++ci) sacc[ci] = (f32x4){0.f, 0.f, 0.f, 0.f};
#pragma unroll
        for (int ci = 0; ci < 4; ++ci) {
#pragma unroll
            for (int kc = 0; kc < 3; ++kc) {
                bf16x8 kh = *(const bf16x8*)(Kh_s + (ci * 16 + r) * 208 + kc * 64 + g * 16);
                bf16x8 kl = *(const bf16x8*)(Kl_s + (ci * 16 + r) * 208 + kc * 64 + g * 16);
                sacc[ci] = __builtin_amdgcn_mfma_f32_16x16x32_bf16(qh[kc], kh, sacc[ci], 0, 0, 0);
                sacc[ci] = __builtin_amdgcn_mfma_f32_16x16x32_bf16(ql[kc], kh, sacc[ci], 0, 0, 0);
                sacc[ci] = __builtin_amdgcn_mfma_f32_16x16x32_bf16(qh[kc], kl, sacc[ci], 0, 0, 0);
            }
        }

        // ---- online softmax. lane holds rows q = w*16 + g*4 + jj, col ci*16+r ----
        float p[4][4];
        float al[4];
#pragma unroll
        for (int jj = 0; jj < 4; ++jj) {
            float s0 = sacc[0][jj] * ATTN_SCALE;
            float s1 = sacc[1][jj] * ATTN_SCALE;
            float s2 = sacc[2][jj] * ATTN_SCALE;
            float s3 = sacc[3][jj] * ATTN_SCALE;
            float mx = fmaxf(fmaxf(s0, s1), fmaxf(s2, s3));
            mx = fmaxf(mx, __shfl_xor(mx, 1));
            mx = fmaxf(mx, __shfl_xor(mx, 2));
            mx = fmaxf(mx, __shfl_xor(mx, 4));
            mx = fmaxf(mx, __shfl_xor(mx, 8));
            float mn = fmaxf(m_i[jj], mx);
            al[jj] = __expf(m_i[jj] - mn);
            p[0][jj] = __expf(s0 - mn);
            p[1][jj] = __expf(s1 - mn);
            p[2][jj] = __expf(s2 - mn);
            p[3][jj] = __expf(s3 - mn);
            float rsm = p[0][jj] + p[1][jj] + p[2][jj] + p[3][jj];
            rsm += __shfl_xor(rsm, 1);
            rsm += __shfl_xor(rsm, 2);
            rsm += __shfl_xor(rsm, 4);
            rsm += __shfl_xor(rsm, 8);
            l_i[jj] = l_i[jj] * al[jj] + rsm;
            m_i[jj] = mn;
        }
        // O rescale
#pragma unroll
        for (int di = 0; di < 6; ++di)
#pragma unroll
            for (int jj = 0; jj < 4; ++jj) o[di][jj] *= al[jj];
        // write P (bf16), rows w*16+g*4+jj, cols ci*16+r (row stride 144 B)
#pragma unroll
        for (int jj = 0; jj < 4; ++jj)
#pragma unroll
            for (int ci = 0; ci < 4; ++ci)
                ((__bf16*)(P_s + (w * 16 + g * 4 + jj) * 144))[ci * 16 + r] = (__bf16)p[ci][jj];
        // same-wave LDS FIFO ordering; keep compiler from reordering
        asm volatile("" ::: "memory");

        // ---- O += P V ----
        bf16x8 pa[2];
#pragma unroll
        for (int kc2 = 0; kc2 < 2; ++kc2)
            pa[kc2] = *(const bf16x8*)(P_s + (w * 16 + r) * 144 + kc2 * 64 + g * 16);
#pragma unroll
        for (int di = 0; di < 6; ++di) {
#pragma unroll
            for (int kc2 = 0; kc2 < 2; ++kc2) {
                bf16x8 vb = *(const bf16x8*)(Vt_s + (di * 16 + r) * 160 + kc2 * 64 + g * 16);
                o[di] = __builtin_amdgcn_mfma_f32_16x16x32_bf16(pa[kc2], vb, o[di], 0, 0, 0);
            }
        }
    }

    // ---- epilogue: out[tok][h*96+d] hi/lo planes ----
    float invl[4];
#pragma unroll
    for (int jj = 0; jj < 4; ++jj) invl[jj] = 1.0f / l_i[jj];
#pragma unroll
    for (int jj = 0; jj < 4; ++jj) {
        size_t tok = (size_t)b * NSEQ + (size_t)qt * 128 + w * 16 + g * 4 + jj;
        size_t base = tok * DIM + h * HD + r;
#pragma unroll
        for (int di = 0; di < 6; ++di) {
            float v = o[di][jj] * invl[jj];
            __bf16 hv = (__bf16)v;
            oH[base + di * 16] = hv;
            oL[base + di * 16] = (__bf16)(v - (float)hv);
        }
    }
}

// ---------------------------------------------------------------------------
// Workspace (fp32 units; total NTOK*3840 floats + flag):
//  R0 [0, NTOK*768)            : ylnH|ylnL -> attnH|attnL -> klnH|klnL (bf16 planes)
//  R1 [NTOK*768, NTOK*3072)    : qkv fp32 [NTOK][2304] -> W0T|W1T|W2T + h planes
//  R2 [NTOK*3072, NTOK*3840)   : WqkvT split -> Khg|Klg bf16 planes -> z fp32
// ---------------------------------------------------------------------------
extern "C" void kernel_launch(void* const* d_in, const int* in_sizes, int n_in,
                              void* d_out, int out_size, void* d_ws, size_t ws_size,
                              hipStream_t stream) {
    const void* x    = d_in[0];
    const void* ln_g = d_in[1];
    const void* ln_b = d_in[2];
    const void* Wqkv = d_in[3];
    const void* bqkv = d_in[4];
    const void* W0   = d_in[5];
    const void* b0   = d_in[6];
    const void* W1   = d_in[7];
    const void* b1   = d_in[8];
    const void* W2   = d_in[9];
    const void* b2   = d_in[10];

    float* ws = (float*)d_ws;
    // R0
    __bf16* ylnH = (__bf16*)ws;
    __bf16* ylnL = ylnH + (size_t)NTOK * DIM;
    __bf16* atnH = ylnH;
    __bf16* atnL = ylnL;
    __bf16* klnH = ylnH;
    __bf16* klnL = ylnL;
    // R1: qkv fp32, then post-attention overlay
    float* qkv = ws + (size_t)NTOK * DIM;      // [NTOK][2304] fp32
    __bf16* r1 = (__bf16*)qkv;                 // qkv dead after attention
    __bf16* W0Th = r1;
    __bf16* W0Tl = W0Th + (size_t)768 * 768;
    __bf16* W1Th = W0Tl + (size_t)768 * 768;   // [HPAD][768]
    __bf16* W1Tl = W1Th + (size_t)HPAD * 768;
    __bf16* W2Th = W1Tl + (size_t)HPAD * 768;  // [768][HPAD]
    __bf16* W2Tl = W2Th + (size_t)768 * HPAD;
    __bf16* hH   = W2Tl + (size_t)768 * HPAD;  // [NTOK][HPAD] + lo plane
    __bf16* hL   = hH + (size_t)NTOK * HPAD;   // total 31.06M bf16 <= 37.75M avail
    // R2
    float* zbuf = ws + (size_t)NTOK * (DIM + 3 * DIM);
    __bf16* WqkvTh = (__bf16*)zbuf;            // dead after step 2
    __bf16* WqkvTl = WqkvTh + (size_t)(3 * DIM) * DIM;
    __bf16* Khg = (__bf16*)zbuf;               // overlays WqkvT after step 2
    __bf16* Klg = Khg + (size_t)64 * NSEQ * HD;  // ends exactly at R2 end

    int* flag = (int*)(ws + (size_t)NTOK * 3840);

    // 0. detect dtype
    detect_kernel<<<1, 1, 0, stream>>>((const unsigned int*)ln_g, flag);
    // 1. y_ln = LN(x)  (split bf16)
    ln_kernel<1><<<NTOK, 256, 0, stream>>>(x, ln_g, ln_b, ylnH, ylnL, flag);
    // 1b. split+transpose Wqkv into R2
    wsplit_kernel<<<dim3(DIM / 32, (3 * DIM) / 32), 256, 0, stream>>>(
        Wqkv, WqkvTh, WqkvTl, DIM, 3 * DIM, DIM, 3 * DIM, flag);
    // 2. qkv = y_ln @ Wqkv + bqkv  (plain coalesced fp32 out)
    gemm_kernel<0, 0, 0><<<dim3((3 * DIM) / 128, NTOK / 128), 256, 0, stream>>>(
        ylnH, ylnL, WqkvTh, WqkvTl, bqkv, nullptr, 0, qkv, 3 * DIM, DIM, 3 * DIM, flag);
    // 2b. K plane conversion pre-pass (WqkvT now dead; Khg/Klg overlay it)
    kconv_kernel<<<dim3(NB * HEADS, NSEQ / 128), 256, 0, stream>>>(qkv, Khg, Klg);
    // 3. MFMA flash attention, QBLK=128 (split bf16 out)
    attn_kernel<<<dim3(NSEQ / 128, NB * HEADS), 512, 0, stream>>>(
        qkv, Khg, Klg, atnH, atnL);
    // 3b. split+transpose W0/W1/W2 into R1 (qkv dead)
    wsplit_kernel<<<dim3(DIM / 32, DIM / 32), 256, 0, stream>>>(
        W0, W0Th, W0Tl, DIM, DIM, DIM, DIM, flag);
    wsplit_kernel<<<dim3(DIM / 32, HPAD / 32), 256, 0, stream>>>(
        W1, W1Th, W1Tl, DIM, HIDDEN, DIM, HPAD, flag);
    wsplit_kernel<<<dim3(HPAD / 32, DIM / 32), 256, 0, stream>>>(
        W2, W2Th, W2Tl, HIDDEN, DIM, HPAD, DIM, flag);
    // 4. z = attn @ W0 + b0 + x  (fp32 out; overwrites Khg/Klg, both dead)
    gemm_kernel<0, 1, 0><<<dim3(DIM / 128, NTOK / 128), 256, 0, stream>>>(
        atnH, atnL, W0Th, W0Tl, b0, x, DIM, zbuf, DIM, DIM, DIM, flag);
    // 5. k_ln = LN(z)  (split bf16)
    ln_kernel<0><<<NTOK, 256, 0, stream>>>(zbuf, ln_g, ln_b, klnH, klnL, flag);
    // 6. h = gelu(k_ln @ W1 + b1)  (split bf16, zero-padded to HPAD)
    gemm_kernel<1, 0, 2><<<dim3(HPAD / 128, NTOK / 128), 256, 0, stream>>>(
        klnH, klnL, W1Th, W1Tl, b1, nullptr, 0, hH, HPAD, DIM, HIDDEN, flag);
    // 7. out = h @ W2 + b2 + z  (flag dtype; K over HPAD, pads zero)
    gemm_kernel<0, 2, 1><<<dim3(DIM / 128, NTOK / 128), 256, 0, stream>>>(
        hH, hL, W2Th, W2Tl, b2, zbuf, DIM, d_out, DIM, HPAD, DIM, flag);
}